// Round 11
// baseline (39.661 us; speedup 1.0000x reference)
//
#include <hip/hip_runtime.h>
#include <stdint.h>

// Problem constants (match reference setup_inputs)
#define BATCH   8
#define CIMG    3
#define HFULL   512
#define WFULL   512
#define HWFULL  (HFULL * WFULL)          // 262144
#define CFEAT   64
#define HE      128
#define WE      128
#define HWE     (HE * WE)                // 16384
#define NSEG    64
#define NBSEG   (BATCH * NSEG)           // 512
#define WALL_COT 0.5f
#define MIN_FRAC 0.01f

#define NBLK    512                      // persistent-ish: 512 blocks x 256 thr, 4 tasks/thread
#define NREP    8                        // replicated global bin sets

// ws float layout:
// [0 .. 12288)        replicated bins: per rep { cnt[512] | sum[512] | pos[512] }
// [12288 .. 12800)    per-block recovery numerator   (plain store)
// [12800 .. 13312)    per-block recovery denominator (plain store)
#define WS_BINS_FLOATS (NREP * 3 * NBSEG)            // 12288
#define WS_BNUM  WS_BINS_FLOATS
#define WS_BDEN  (WS_BNUM + NBLK)
#define WS_ZERO_FLOATS WS_BINS_FLOATS

typedef float vf4 __attribute__((ext_vector_type(4)));

// Issue one tile's 15 vector loads into named register set S, pin ALL results
// simultaneously live, fence the scheduler (nothing may hoist above), then
// advance the per-thread pointers. Order ISSUE(k+1) before CONSUME(k) =>
// compiler emits a COUNTED vmcnt for tile k while k+1's loads stay in flight.
#define ISSUE(S)                                                        \
    e##S##0 = *(const vf4*)(ep);                                        \
    e##S##1 = *(const vf4*)(ep + HWE);                                  \
    e##S##2 = *(const vf4*)(ep + 2 * HWE);                              \
    e##S##3 = *(const vf4*)(ep + 3 * HWE);                              \
    d##S##0 = *(const vf4*)(dp);                                        \
    d##S##1 = *(const vf4*)(dp + HWE);                                  \
    d##S##2 = *(const vf4*)(dp + 2 * HWE);                              \
    d##S##3 = *(const vf4*)(dp + 3 * HWE);                              \
    m##S    = *(const vf4*)(mpp);                                       \
    o##S##0 = *(const vf4*)(obp);                                       \
    o##S##1 = *(const vf4*)(obp + HWFULL);                              \
    o##S##2 = *(const vf4*)(obp + 2 * HWFULL);                          \
    q##S##0 = *(const vf4*)(ibp);                                       \
    q##S##1 = *(const vf4*)(ibp + HWFULL);                              \
    q##S##2 = *(const vf4*)(ibp + 2 * HWFULL);                          \
    asm volatile("" ::                                                  \
        "v"(e##S##0), "v"(e##S##1), "v"(e##S##2), "v"(e##S##3),         \
        "v"(d##S##0), "v"(d##S##1), "v"(d##S##2), "v"(d##S##3),         \
        "v"(m##S), "v"(o##S##0), "v"(o##S##1), "v"(o##S##2),            \
        "v"(q##S##0), "v"(q##S##1), "v"(q##S##2));                      \
    __builtin_amdgcn_sched_barrier(0);                                  \
    ep  += (size_t)16 * HWE;  dp  += (size_t)16 * HWE;                  \
    obp += (size_t)2 * CIMG * HWFULL;                                   \
    ibp += (size_t)2 * CIMG * HWFULL;                                   \
    mpp += (size_t)2 * HWFULL;

#define BPIX(mv, a0, a1, a2, b0, b1, b2)                                \
    {                                                                   \
        float tgt, dd, mse = 0.f;                                       \
        tgt = ((mv) >= WALL_COT) ? 0.f : (b0); dd = (a0) - tgt; mse += dd*dd; \
        tgt = ((mv) >= WALL_COT) ? 0.f : (b1); dd = (a1) - tgt; mse += dd*dd; \
        tgt = ((mv) >= WALL_COT) ? 0.f : (b2); dd = (a2) - tgt; mse += dd*dd; \
        if ((mv) > 0.f) { num += mse; den += 1.f; }                     \
    }

// Bind pasted names to plain aliases FIRST (## must not appear in args to a
// nested function-like macro), then use ordinary tokens.
#define CONSUME(S)                                                      \
    {                                                                   \
        const vf4 Xm  = m##S;                                           \
        const vf4 Xo0 = o##S##0, Xo1 = o##S##1, Xo2 = o##S##2;          \
        const vf4 Xq0 = q##S##0, Xq1 = q##S##1, Xq2 = q##S##2;          \
        const vf4 Xe0 = e##S##0, Xe1 = e##S##1, Xe2 = e##S##2, Xe3 = e##S##3; \
        const vf4 Xd0 = d##S##0, Xd1 = d##S##1, Xd2 = d##S##2, Xd3 = d##S##3; \
        BPIX(Xm.x, Xo0.x, Xo1.x, Xo2.x, Xq0.x, Xq1.x, Xq2.x)            \
        BPIX(Xm.y, Xo0.y, Xo1.y, Xo2.y, Xq0.y, Xq1.y, Xq2.y)            \
        BPIX(Xm.z, Xo0.z, Xo1.z, Xo2.z, Xq0.z, Xq1.z, Xq2.z)            \
        BPIX(Xm.w, Xo0.w, Xo1.w, Xo2.w, Xq0.w, Xq1.w, Xq2.w)            \
        float t0, t1, t2, t3;                                           \
        t0 = Xe0.x - Xd0.x; t1 = Xe1.x - Xd1.x;                         \
        t2 = Xe2.x - Xd2.x; t3 = Xe3.x - Xd3.x;                         \
        const float p0 = (t0*t0 + t1*t1 + t2*t2 + t3*t3) * (1.0f / (float)CFEAT); \
        t0 = Xe0.y - Xd0.y; t1 = Xe1.y - Xd1.y;                         \
        t2 = Xe2.y - Xd2.y; t3 = Xe3.y - Xd3.y;                         \
        const float p1 = (t0*t0 + t1*t1 + t2*t2 + t3*t3) * (1.0f / (float)CFEAT); \
        t0 = Xe0.z - Xd0.z; t1 = Xe1.z - Xd1.z;                         \
        t2 = Xe2.z - Xd2.z; t3 = Xe3.z - Xd3.z;                         \
        const float p2 = (t0*t0 + t1*t1 + t2*t2 + t3*t3) * (1.0f / (float)CFEAT); \
        t0 = Xe0.w - Xd0.w; t1 = Xe1.w - Xd1.w;                         \
        t2 = Xe2.w - Xd2.w; t3 = Xe3.w - Xd3.w;                         \
        const float p3 = (t0*t0 + t1*t1 + t2*t2 + t3*t3) * (1.0f / (float)CFEAT); \
        atomicAdd(&s_sumW[w][s0], p0);                                  \
        atomicAdd(&s_sumW[w][s1], p1);                                  \
        atomicAdd(&s_sumW[w][s2], p2);                                  \
        atomicAdd(&s_sumW[w][s3], p3);                                  \
    }

__global__ __launch_bounds__(256, 2) void confloss_main_kernel(
    const float* __restrict__ outputs, const float* __restrict__ inputs,
    const float* __restrict__ enc1,    const float* __restrict__ dec1,
    const float* __restrict__ masks,   const int* __restrict__ segs,
    float* __restrict__ ws)
{
    const int tid = threadIdx.x;
    const int w   = tid >> 6;            // wave id [0,4)
    const int l   = tid & 63;            // lane id
    const int gid = blockIdx.x * 256 + tid;   // [0, 131072)

    // per-wave LDS bin replicas: zeroed by own wave, no init barrier needed
    __shared__ float s_sumW[4][NSEG];
    __shared__ float s_cntW[4][NSEG];
    __shared__ float s_posW[4][NSEG];
    __shared__ float s_rn[4], s_rd[4];
    s_sumW[w][l] = 0.f; s_cntW[w][l] = 0.f; s_posW[w][l] = 0.f;

    // ---- task decode (fixed per thread; iter t advances c by +4, batch by +2) ----
    const int g  = gid & 32767;          // px-group, SAME for all 4 iterations
    const int c0 = gid >> 15;            // starting channel-slice [0,4)
    const int ba = g >> 12;              // batch for A (block-uniform)
    const int ra = (g & 4095) * 4;       // px offset in 128x128 plane
    const int b0 = gid >> 16;            // starting batch for B: {0,1}
    const int rb = (gid & 65535) * 4;    // px offset in 512x512 plane

    const float* ep  = enc1 + ((size_t)ba * CFEAT + (size_t)c0 * 4) * HWE + ra;
    const float* dp  = dec1 + ((size_t)ba * CFEAT + (size_t)c0 * 4) * HWE + ra;
    const float* obp = outputs + (size_t)b0 * (CIMG * HWFULL) + rb;
    const float* ibp = inputs  + (size_t)b0 * (CIMG * HWFULL) + rb;
    const float* mpp = masks   + (size_t)b0 * HWFULL + rb;

    // ---- seg/mask gather ONCE (shared by all 4 iterations) ----
    const int ya = ra >> 7, xa = ra & (WE - 1);
    const int fb = ba * HWFULL + (ya * 4) * WFULL + xa * 4;
    const int s0 = segs[fb], s1 = segs[fb + 4], s2 = segs[fb + 8], s3 = segs[fb + 12];
    const bool dutyA = ((g & 3) == c0);  // exactly one of the 4 g-sharing threads
    float mk0 = 1.f, mk1 = 1.f, mk2 = 1.f, mk3 = 1.f;
    if (dutyA) {
        mk0 = masks[fb];     mk1 = masks[fb + 4];
        mk2 = masks[fb + 8]; mk3 = masks[fb + 12];
    }

    float num = 0.f, den = 0.f;
    vf4 eA0, eA1, eA2, eA3, dA0, dA1, dA2, dA3, mA, oA0, oA1, oA2, qA0, qA1, qA2;
    vf4 eB0, eB1, eB2, eB3, dB0, dB1, dB2, dB3, mB, oB0, oB1, oB2, qB0, qB1, qB2;

    // ---- 2-deep pipelined loop over 4 tiles (hand-unrolled, named sets) ----
    ISSUE(A)                 // tile 0
    ISSUE(B)                 // tile 1 in flight
    CONSUME(A)               // tile 0 (counted wait; tile 1 stays outstanding)
    ISSUE(A)                 // tile 2 in flight
    CONSUME(B)               // tile 1
    ISSUE(B)                 // tile 3 in flight
    CONSUME(A)               // tile 2
    CONSUME(B)               // tile 3

    // ---- cnt/pos binned once per px-group ----
    if (dutyA) {
        atomicAdd(&s_cntW[w][s0], 1.f); if (mk0 > 0.f && mk0 < WALL_COT) atomicAdd(&s_posW[w][s0], 1.f);
        atomicAdd(&s_cntW[w][s1], 1.f); if (mk1 > 0.f && mk1 < WALL_COT) atomicAdd(&s_posW[w][s1], 1.f);
        atomicAdd(&s_cntW[w][s2], 1.f); if (mk2 > 0.f && mk2 < WALL_COT) atomicAdd(&s_posW[w][s2], 1.f);
        atomicAdd(&s_cntW[w][s3], 1.f); if (mk3 > 0.f && mk3 < WALL_COT) atomicAdd(&s_posW[w][s3], 1.f);
    }

    // ---- B wave reduce -> per-block partial ----
#pragma unroll
    for (int off = 32; off >= 1; off >>= 1) {
        num += __shfl_down(num, off);
        den += __shfl_down(den, off);
    }
    if (l == 0) { s_rn[w] = num; s_rd[w] = den; }
    __syncthreads();

    if (tid == 0) {
        ws[WS_BNUM + blockIdx.x] = s_rn[0] + s_rn[1] + s_rn[2] + s_rn[3];
        ws[WS_BDEN + blockIdx.x] = s_rd[0] + s_rd[1] + s_rd[2] + s_rd[3];
    }
    if (tid < NSEG) {
        const int rep = blockIdx.x & (NREP - 1);
        float* bins = ws + rep * (3 * NBSEG);
        const int gb = ba * NSEG + tid;
        const float sv = s_sumW[0][tid] + s_sumW[1][tid] + s_sumW[2][tid] + s_sumW[3][tid];
        const float cv = s_cntW[0][tid] + s_cntW[1][tid] + s_cntW[2][tid] + s_cntW[3][tid];
        const float pv = s_posW[0][tid] + s_posW[1][tid] + s_posW[2][tid] + s_posW[3][tid];
        if (sv != 0.f) atomicAdd(&bins[NBSEG + gb], sv);
        if (cv != 0.f) atomicAdd(&bins[gb], cv);
        if (pv != 0.f) atomicAdd(&bins[2 * NBSEG + gb], pv);
    }
}

__global__ __launch_bounds__(512) void confloss_finalize_kernel(
    const float* __restrict__ ws, float* __restrict__ out)
{
    const int t = threadIdx.x;   // one per (b,seg); NBLK/512 B-partials each
    float rn = 0.f, rd = 0.f;
#pragma unroll
    for (int k = 0; k < NBLK / 512; ++k) {
        rn += ws[WS_BNUM + t + k * 512];
        rd += ws[WS_BDEN + t + k * 512];
    }
    float cnt = 0.f, sum = 0.f, pos = 0.f;
#pragma unroll
    for (int rep = 0; rep < NREP; ++rep) {
        const float* bins = ws + rep * (3 * NBSEG);
        cnt += bins[t];
        sum += bins[NBSEG + t];
        pos += bins[2 * NBSEG + t];
    }
    const float safe = fmaxf(cnt, 1.0f);
    const float mean = sum / safe;
    const bool valid = (cnt / (float)HWE) >= MIN_FRAC;
    const bool posf  = (pos / safe) > MIN_FRAC;
    float sel = (valid && posf) ? 1.0f : 0.0f;
    float val = mean * sel;

#pragma unroll
    for (int off = 32; off >= 1; off >>= 1) {
        val += __shfl_down(val, off);
        sel += __shfl_down(sel, off);
        rn  += __shfl_down(rn,  off);
        rd  += __shfl_down(rd,  off);
    }
    __shared__ float sv[8], ss[8], sn[8], sd[8];
    const int wid = t >> 6;
    if ((t & 63) == 0) { sv[wid] = val; ss[wid] = sel; sn[wid] = rn; sd[wid] = rd; }
    __syncthreads();
    if (t == 0) {
        float tv = 0.f, ts = 0.f, tn = 0.f, td = 0.f;
#pragma unroll
        for (int k = 0; k < 8; ++k) { tv += sv[k]; ts += ss[k]; tn += sn[k]; td += sd[k]; }
        const float flat_pos_mean = tv / fmaxf(ts, 1.0f);
        const float loss_recov = tn / fmaxf(td, 1.0f);
        out[0] = loss_recov + flat_pos_mean;
    }
}

extern "C" void kernel_launch(void* const* d_in, const int* in_sizes, int n_in,
                              void* d_out, int out_size, void* d_ws, size_t ws_size,
                              hipStream_t stream) {
    const float* outputs = (const float*)d_in[0];
    const float* inputs  = (const float*)d_in[1];
    const float* enc1    = (const float*)d_in[2];
    const float* dec1    = (const float*)d_in[3];
    const float* masks   = (const float*)d_in[4];
    const int*   segs    = (const int*)d_in[5];
    float* ws  = (float*)d_ws;
    float* out = (float*)d_out;

    // atomic bins must be zeroed every call
    hipMemsetAsync(ws, 0, WS_ZERO_FLOATS * sizeof(float), stream);

    confloss_main_kernel<<<NBLK, 256, 0, stream>>>(
        outputs, inputs, enc1, dec1, masks, segs, ws);
    confloss_finalize_kernel<<<1, 512, 0, stream>>>(ws, out);
}

// Round 12
// 37.842 us; speedup vs baseline: 1.0481x; 1.0481x over previous
//
#include <hip/hip_runtime.h>
#include <stdint.h>

// Problem constants (match reference setup_inputs)
#define BATCH   8
#define CIMG    3
#define HFULL   512
#define WFULL   512
#define HWFULL  (HFULL * WFULL)          // 262144
#define CFEAT   64
#define HE      128
#define WE      128
#define HWE     (HE * WE)                // 16384
#define NSEG    64
#define NBSEG   (BATCH * NSEG)           // 512
#define WALL_COT 0.5f
#define MIN_FRAC 0.01f

#define NBLK    1024                     // 1024 blocks x 256 threads, 2 stages/thread
#define RECF    208                      // per-block record: cnt[64]|sum[64]|pos[64]|rn|rd|pad
// ws floats used: NBLK * RECF = 212992 (~852 KB). NO zeroing needed: every slot
// read by finalize is written unconditionally by main every call.

typedef float vf4 __attribute__((ext_vector_type(4)));

__global__ __launch_bounds__(256) void confloss_main_kernel(
    const float* __restrict__ outputs, const float* __restrict__ inputs,
    const float* __restrict__ enc1,    const float* __restrict__ dec1,
    const float* __restrict__ masks,   const int* __restrict__ segs,
    float* __restrict__ ws)
{
    const int tid = threadIdx.x;
    const int w   = tid >> 6;            // wave id [0,4)
    const int l   = tid & 63;            // lane id
    const int i   = blockIdx.x * 256 + tid;   // [0, 262144)

    // per-wave LDS bin replicas: zeroed by own wave -> no init barrier
    __shared__ float s_sumW[4][NSEG];
    __shared__ float s_cntW[4][NSEG];
    __shared__ float s_posW[4][NSEG];
    __shared__ float s_rn[4], s_rd[4];
    s_sumW[w][l] = 0.f; s_cntW[w][l] = 0.f; s_posW[w][l] = 0.f;

    // ---- A decode: stage k handles channel-slice c+8k of the SAME px-group ----
    const int g  = i & 32767;            // px-group [0,32768)
    const int c  = i >> 15;              // [0,8) (stage1 uses c+8); block-uniform
    const int ba = g >> 12;              // batch (block-uniform, same both stages)
    const int ra = (g & 4095) * 4;       // px offset in 128x128 plane
    const size_t abase = ((size_t)ba * CFEAT + (size_t)c * 4) * HWE + ra;
    const float* ep0 = enc1 + abase;
    const float* dp0 = dec1 + abase;
    const float* ep1 = ep0 + (size_t)32 * HWE;   // c+8 -> +32 channels
    const float* dp1 = dp0 + (size_t)32 * HWE;

    // ---- B decode: stage k handles batch bb+4k at the same plane offset ----
    const int bb = i >> 16;              // [0,4); block-uniform
    const int rb = (i & 65535) * 4;
    const float* ob0 = outputs + (size_t)bb * (CIMG * HWFULL) + rb;
    const float* ib0 = inputs  + (size_t)bb * (CIMG * HWFULL) + rb;
    const float* ob1 = ob0 + (size_t)4 * (CIMG * HWFULL);
    const float* ib1 = ib0 + (size_t)4 * (CIMG * HWFULL);
    const float* mp0 = masks + (size_t)bb * HWFULL + rb;
    const float* mp1 = mp0 + (size_t)4 * HWFULL;

    // seg/mask gather (once; shared by both stages)
    const int ya = ra >> 7, xa = ra & (WE - 1);
    const int fb = ba * HWFULL + (ya * 4) * WFULL + xa * 4;
    const int gl = g & 15;
    const bool duty = (gl == c) || (gl == c + 8);  // counted exactly once over all stages

    // ================= STAGE 0 ISSUE =================
    const vf4 e00 = *(const vf4*)(ep0);
    const vf4 e01 = *(const vf4*)(ep0 + HWE);
    const vf4 e02 = *(const vf4*)(ep0 + 2 * HWE);
    const vf4 e03 = *(const vf4*)(ep0 + 3 * HWE);
    const vf4 d00 = *(const vf4*)(dp0);
    const vf4 d01 = *(const vf4*)(dp0 + HWE);
    const vf4 d02 = *(const vf4*)(dp0 + 2 * HWE);
    const vf4 d03 = *(const vf4*)(dp0 + 3 * HWE);
    const vf4 mB0 = *(const vf4*)(mp0);
    const vf4 o00 = *(const vf4*)(ob0);
    const vf4 o01 = *(const vf4*)(ob0 + HWFULL);
    const vf4 o02 = *(const vf4*)(ob0 + 2 * HWFULL);
    const vf4 i00 = *(const vf4*)(ib0);
    const vf4 i01 = *(const vf4*)(ib0 + HWFULL);
    const vf4 i02 = *(const vf4*)(ib0 + 2 * HWFULL);
    const int s0 = segs[fb], s1 = segs[fb + 4], s2 = segs[fb + 8], s3 = segs[fb + 12];
    float mk0 = 1.f, mk1 = 1.f, mk2 = 1.f, mk3 = 1.f;
    if (duty) {
        mk0 = masks[fb];     mk1 = masks[fb + 4];
        mk2 = masks[fb + 8]; mk3 = masks[fb + 12];
    }
    // SINGLE pin consuming every stage-0 value simultaneously
    asm volatile("" ::
        "v"(e00), "v"(e01), "v"(e02), "v"(e03),
        "v"(d00), "v"(d01), "v"(d02), "v"(d03),
        "v"(mB0), "v"(o00), "v"(o01), "v"(o02),
        "v"(i00), "v"(i01), "v"(i02));
    asm volatile("" :: "v"(s0), "v"(s1), "v"(s2), "v"(s3),
                       "v"(mk0), "v"(mk1), "v"(mk2), "v"(mk3));

    // ================= STAGE 1 ISSUE (in flight while stage 0 is consumed) ====
    const vf4 e10 = *(const vf4*)(ep1);
    const vf4 e11 = *(const vf4*)(ep1 + HWE);
    const vf4 e12 = *(const vf4*)(ep1 + 2 * HWE);
    const vf4 e13 = *(const vf4*)(ep1 + 3 * HWE);
    const vf4 d10 = *(const vf4*)(dp1);
    const vf4 d11 = *(const vf4*)(dp1 + HWE);
    const vf4 d12 = *(const vf4*)(dp1 + 2 * HWE);
    const vf4 d13 = *(const vf4*)(dp1 + 3 * HWE);
    const vf4 mB1 = *(const vf4*)(mp1);
    const vf4 o10 = *(const vf4*)(ob1);
    const vf4 o11 = *(const vf4*)(ob1 + HWFULL);
    const vf4 o12 = *(const vf4*)(ob1 + 2 * HWFULL);
    const vf4 i10 = *(const vf4*)(ib1);
    const vf4 i11 = *(const vf4*)(ib1 + HWFULL);
    const vf4 i12 = *(const vf4*)(ib1 + 2 * HWFULL);
    asm volatile("" ::
        "v"(e10), "v"(e11), "v"(e12), "v"(e13),
        "v"(d10), "v"(d11), "v"(d12), "v"(d13),
        "v"(mB1), "v"(o10), "v"(o11), "v"(o12),
        "v"(i10), "v"(i11), "v"(i12));

    // ================= CONSUME B (both stages), registers only =================
    float num = 0.f, den = 0.f;
#define BPIX(mv, a0, a1, a2, b0, b1, b2)                                   \
    {                                                                       \
        float tgt, dd, mse = 0.f;                                           \
        tgt = ((mv) >= WALL_COT) ? 0.f : (b0); dd = (a0) - tgt; mse += dd*dd; \
        tgt = ((mv) >= WALL_COT) ? 0.f : (b1); dd = (a1) - tgt; mse += dd*dd; \
        tgt = ((mv) >= WALL_COT) ? 0.f : (b2); dd = (a2) - tgt; mse += dd*dd; \
        if ((mv) > 0.f) { num += mse; den += 1.f; }                         \
    }
    BPIX(mB0.x, o00.x, o01.x, o02.x, i00.x, i01.x, i02.x)
    BPIX(mB0.y, o00.y, o01.y, o02.y, i00.y, i01.y, i02.y)
    BPIX(mB0.z, o00.z, o01.z, o02.z, i00.z, i01.z, i02.z)
    BPIX(mB0.w, o00.w, o01.w, o02.w, i00.w, i01.w, i02.w)
    BPIX(mB1.x, o10.x, o11.x, o12.x, i10.x, i11.x, i12.x)
    BPIX(mB1.y, o10.y, o11.y, o12.y, i10.y, i11.y, i12.y)
    BPIX(mB1.z, o10.z, o11.z, o12.z, i10.z, i11.z, i12.z)
    BPIX(mB1.w, o10.w, o11.w, o12.w, i10.w, i11.w, i12.w)
#undef BPIX

    // ====== CONSUME A: 8 channels per px (stage0 + stage1 merged in regs) ======
    {
        float t0, t1, t2, t3, u0, u1, u2, u3;
#define APIX(f)                                                             \
        t0 = e00.f - d00.f; t1 = e01.f - d01.f;                             \
        t2 = e02.f - d02.f; t3 = e03.f - d03.f;                             \
        u0 = e10.f - d10.f; u1 = e11.f - d11.f;                             \
        u2 = e12.f - d12.f; u3 = e13.f - d13.f;
        APIX(x)
        const float p0 = (t0*t0 + t1*t1 + t2*t2 + t3*t3 +
                          u0*u0 + u1*u1 + u2*u2 + u3*u3) * (1.0f / (float)CFEAT);
        APIX(y)
        const float p1 = (t0*t0 + t1*t1 + t2*t2 + t3*t3 +
                          u0*u0 + u1*u1 + u2*u2 + u3*u3) * (1.0f / (float)CFEAT);
        APIX(z)
        const float p2 = (t0*t0 + t1*t1 + t2*t2 + t3*t3 +
                          u0*u0 + u1*u1 + u2*u2 + u3*u3) * (1.0f / (float)CFEAT);
        APIX(w)
        const float p3 = (t0*t0 + t1*t1 + t2*t2 + t3*t3 +
                          u0*u0 + u1*u1 + u2*u2 + u3*u3) * (1.0f / (float)CFEAT);
#undef APIX
        atomicAdd(&s_sumW[w][s0], p0);
        atomicAdd(&s_sumW[w][s1], p1);
        atomicAdd(&s_sumW[w][s2], p2);
        atomicAdd(&s_sumW[w][s3], p3);
        if (duty) {
            atomicAdd(&s_cntW[w][s0], 1.f); if (mk0 > 0.f && mk0 < WALL_COT) atomicAdd(&s_posW[w][s0], 1.f);
            atomicAdd(&s_cntW[w][s1], 1.f); if (mk1 > 0.f && mk1 < WALL_COT) atomicAdd(&s_posW[w][s1], 1.f);
            atomicAdd(&s_cntW[w][s2], 1.f); if (mk2 > 0.f && mk2 < WALL_COT) atomicAdd(&s_posW[w][s2], 1.f);
            atomicAdd(&s_cntW[w][s3], 1.f); if (mk3 > 0.f && mk3 < WALL_COT) atomicAdd(&s_posW[w][s3], 1.f);
        }
    }

    // ---- B wave reduce -> per-block partial ----
#pragma unroll
    for (int off = 32; off >= 1; off >>= 1) {
        num += __shfl_down(num, off);
        den += __shfl_down(den, off);
    }
    if (l == 0) { s_rn[w] = num; s_rd[w] = den; }
    __syncthreads();

    // ---- per-block record: plain coalesced stores, NO atomics, NO pre-zeroing ----
    float* rec = ws + (size_t)blockIdx.x * RECF;
    if (tid < NSEG) {
        const float cv = s_cntW[0][tid] + s_cntW[1][tid] + s_cntW[2][tid] + s_cntW[3][tid];
        const float sv = s_sumW[0][tid] + s_sumW[1][tid] + s_sumW[2][tid] + s_sumW[3][tid];
        const float pv = s_posW[0][tid] + s_posW[1][tid] + s_posW[2][tid] + s_posW[3][tid];
        rec[tid]       = cv;
        rec[64 + tid]  = sv;
        rec[128 + tid] = pv;
    }
    if (tid == 0) {
        rec[192] = s_rn[0] + s_rn[1] + s_rn[2] + s_rn[3];
        rec[193] = s_rd[0] + s_rd[1] + s_rd[2] + s_rd[3];
    }
}

__global__ __launch_bounds__(512) void confloss_finalize_kernel(
    const float* __restrict__ ws, float* __restrict__ out)
{
    const int t  = threadIdx.x;          // (b,seg)
    const int b  = t >> 6;
    const int sg = t & 63;

    // blocks with batch b: blk = (k&15) | (b<<4) | ((k>>4)<<7), k in [0,128)
    float cnt = 0.f, sum = 0.f, pos = 0.f;
#pragma unroll 8
    for (int k = 0; k < 128; ++k) {
        const int blk = (k & 15) | (b << 4) | ((k >> 4) << 7);
        const float* rec = ws + (size_t)blk * RECF;
        cnt += rec[sg];
        sum += rec[64 + sg];
        pos += rec[128 + sg];
    }
    // B partials: each thread sums 2 of the 1024 records
    float rn = ws[(size_t)(2 * t) * RECF + 192] + ws[(size_t)(2 * t + 1) * RECF + 192];
    float rd = ws[(size_t)(2 * t) * RECF + 193] + ws[(size_t)(2 * t + 1) * RECF + 193];

    const float safe = fmaxf(cnt, 1.0f);
    const float mean = sum / safe;
    const bool valid = (cnt / (float)HWE) >= MIN_FRAC;
    const bool posf  = (pos / safe) > MIN_FRAC;
    float sel = (valid && posf) ? 1.0f : 0.0f;
    float val = mean * sel;

#pragma unroll
    for (int off = 32; off >= 1; off >>= 1) {
        val += __shfl_down(val, off);
        sel += __shfl_down(sel, off);
        rn  += __shfl_down(rn,  off);
        rd  += __shfl_down(rd,  off);
    }
    __shared__ float sv[8], ss[8], sn[8], sd[8];
    const int wid = t >> 6;
    if ((t & 63) == 0) { sv[wid] = val; ss[wid] = sel; sn[wid] = rn; sd[wid] = rd; }
    __syncthreads();
    if (t == 0) {
        float tv = 0.f, ts = 0.f, tn = 0.f, td = 0.f;
#pragma unroll
        for (int k = 0; k < 8; ++k) { tv += sv[k]; ts += ss[k]; tn += sn[k]; td += sd[k]; }
        const float flat_pos_mean = tv / fmaxf(ts, 1.0f);
        const float loss_recov = tn / fmaxf(td, 1.0f);
        out[0] = loss_recov + flat_pos_mean;
    }
}

extern "C" void kernel_launch(void* const* d_in, const int* in_sizes, int n_in,
                              void* d_out, int out_size, void* d_ws, size_t ws_size,
                              hipStream_t stream) {
    const float* outputs = (const float*)d_in[0];
    const float* inputs  = (const float*)d_in[1];
    const float* enc1    = (const float*)d_in[2];
    const float* dec1    = (const float*)d_in[3];
    const float* masks   = (const float*)d_in[4];
    const int*   segs    = (const int*)d_in[5];
    float* ws  = (float*)d_ws;
    float* out = (float*)d_out;

    // 2-node graph: no memset (per-block records are fully overwritten each call)
    confloss_main_kernel<<<NBLK, 256, 0, stream>>>(
        outputs, inputs, enc1, dec1, masks, segs, ws);
    confloss_finalize_kernel<<<1, 512, 0, stream>>>(ws, out);
}

// Round 13
// 36.352 us; speedup vs baseline: 1.0910x; 1.0410x over previous
//
#include <hip/hip_runtime.h>
#include <stdint.h>

// Problem constants (match reference setup_inputs)
#define BATCH   8
#define CIMG    3
#define HFULL   512
#define WFULL   512
#define HWFULL  (HFULL * WFULL)          // 262144
#define CFEAT   64
#define HE      128
#define WE      128
#define HWE     (HE * WE)                // 16384
#define NSEG    64
#define NBSEG   (BATCH * NSEG)           // 512
#define WALL_COT 0.5f
#define MIN_FRAC 0.01f

#define NBLK    1024                     // 1024 blocks x 256 threads, 2 stages/thread
#define NREP    8                        // replicated global bin sets

// ws float layout:
// [0 .. 12288)        replicated bins: per rep { cnt[512] | sum[512] | pos[512] }
// [12288 .. 13312)    per-block recovery numerator   (plain store)
// [13312 .. 14336)    per-block recovery denominator (plain store)
#define WS_BINS_FLOATS (NREP * 3 * NBSEG)            // 12288
#define WS_BNUM  WS_BINS_FLOATS
#define WS_BDEN  (WS_BNUM + NBLK)
#define WS_ZERO_FLOATS WS_BINS_FLOATS

typedef float vf4 __attribute__((ext_vector_type(4)));

// nontemporal 16B load: stream around L2/L3 (no reuse within a dispatch;
// shifts supply from the L3 port to the idle HBM channels)
#define NTL(p) __builtin_nontemporal_load((const vf4*)(p))

__global__ __launch_bounds__(256) void confloss_main_kernel(
    const float* __restrict__ outputs, const float* __restrict__ inputs,
    const float* __restrict__ enc1,    const float* __restrict__ dec1,
    const float* __restrict__ masks,   const int* __restrict__ segs,
    float* __restrict__ ws)
{
    const int tid = threadIdx.x;
    const int w   = tid >> 6;            // wave id [0,4)
    const int l   = tid & 63;            // lane id
    const int i   = blockIdx.x * 256 + tid;   // [0, 262144)

    __shared__ float s_sumW[4][NSEG];    // per-wave sum bins
    __shared__ float s_cnt[NSEG], s_pos[NSEG];
    __shared__ float s_rn[4], s_rd[4];
    s_sumW[w][l] = 0.f;
    if (tid < NSEG) { s_cnt[tid] = 0.f; s_pos[tid] = 0.f; }
    __syncthreads();

    // ---- A decode: stage k handles channel-slice c+8k of the SAME px-group ----
    const int g  = i & 32767;            // px-group [0,32768)
    const int c  = i >> 15;              // [0,8) (stage1 uses c+8); block-uniform
    const int ba = g >> 12;              // batch (block-uniform, same both stages)
    const int ra = (g & 4095) * 4;       // px offset in 128x128 plane
    const size_t abase = ((size_t)ba * CFEAT + (size_t)c * 4) * HWE + ra;
    const float* ep0 = enc1 + abase;
    const float* dp0 = dec1 + abase;
    const float* ep1 = ep0 + (size_t)32 * HWE;   // c+8 -> +32 channels
    const float* dp1 = dp0 + (size_t)32 * HWE;

    // ---- B decode: stage k handles batch bb+4k at the same plane offset ----
    const int bb = i >> 16;              // [0,4); block-uniform
    const int rb = (i & 65535) * 4;
    const float* ob0 = outputs + (size_t)bb * (CIMG * HWFULL) + rb;
    const float* ib0 = inputs  + (size_t)bb * (CIMG * HWFULL) + rb;
    const float* ob1 = ob0 + (size_t)4 * (CIMG * HWFULL);
    const float* ib1 = ib0 + (size_t)4 * (CIMG * HWFULL);
    const float* mp0 = masks + (size_t)bb * HWFULL + rb;
    const float* mp1 = mp0 + (size_t)4 * HWFULL;

    // seg/mask gather (once; shared by both stages) — cached path (tiny, reused)
    const int ya = ra >> 7, xa = ra & (WE - 1);
    const int fb = ba * HWFULL + (ya * 4) * WFULL + xa * 4;
    const int gl = g & 15;
    const bool duty = (gl == c) || (gl == c + 8);  // counted exactly once over all stages

    // ================= STAGE 0 ISSUE =================
    const vf4 e00 = NTL(ep0);
    const vf4 e01 = NTL(ep0 + HWE);
    const vf4 e02 = NTL(ep0 + 2 * HWE);
    const vf4 e03 = NTL(ep0 + 3 * HWE);
    const vf4 d00 = NTL(dp0);
    const vf4 d01 = NTL(dp0 + HWE);
    const vf4 d02 = NTL(dp0 + 2 * HWE);
    const vf4 d03 = NTL(dp0 + 3 * HWE);
    const vf4 mB0 = NTL(mp0);
    const vf4 o00 = NTL(ob0);
    const vf4 o01 = NTL(ob0 + HWFULL);
    const vf4 o02 = NTL(ob0 + 2 * HWFULL);
    const vf4 i00 = NTL(ib0);
    const vf4 i01 = NTL(ib0 + HWFULL);
    const vf4 i02 = NTL(ib0 + 2 * HWFULL);
    const int s0 = segs[fb], s1 = segs[fb + 4], s2 = segs[fb + 8], s3 = segs[fb + 12];
    float mk0 = 1.f, mk1 = 1.f, mk2 = 1.f, mk3 = 1.f;
    if (duty) {
        mk0 = masks[fb];     mk1 = masks[fb + 4];
        mk2 = masks[fb + 8]; mk3 = masks[fb + 12];
    }
    // SINGLE pin consuming every stage-0 value simultaneously
    asm volatile("" ::
        "v"(e00), "v"(e01), "v"(e02), "v"(e03),
        "v"(d00), "v"(d01), "v"(d02), "v"(d03),
        "v"(mB0), "v"(o00), "v"(o01), "v"(o02),
        "v"(i00), "v"(i01), "v"(i02));
    asm volatile("" :: "v"(s0), "v"(s1), "v"(s2), "v"(s3),
                       "v"(mk0), "v"(mk1), "v"(mk2), "v"(mk3));

    // ================= STAGE 1 ISSUE (in flight while stage 0 is consumed) ====
    const vf4 e10 = NTL(ep1);
    const vf4 e11 = NTL(ep1 + HWE);
    const vf4 e12 = NTL(ep1 + 2 * HWE);
    const vf4 e13 = NTL(ep1 + 3 * HWE);
    const vf4 d10 = NTL(dp1);
    const vf4 d11 = NTL(dp1 + HWE);
    const vf4 d12 = NTL(dp1 + 2 * HWE);
    const vf4 d13 = NTL(dp1 + 3 * HWE);
    const vf4 mB1 = NTL(mp1);
    const vf4 o10 = NTL(ob1);
    const vf4 o11 = NTL(ob1 + HWFULL);
    const vf4 o12 = NTL(ob1 + 2 * HWFULL);
    const vf4 i10 = NTL(ib1);
    const vf4 i11 = NTL(ib1 + HWFULL);
    const vf4 i12 = NTL(ib1 + 2 * HWFULL);
    asm volatile("" ::
        "v"(e10), "v"(e11), "v"(e12), "v"(e13),
        "v"(d10), "v"(d11), "v"(d12), "v"(d13),
        "v"(mB1), "v"(o10), "v"(o11), "v"(o12),
        "v"(i10), "v"(i11), "v"(i12));

    // ================= CONSUME B (both stages), registers only =================
    float num = 0.f, den = 0.f;
#define BPIX(mv, a0, a1, a2, b0, b1, b2)                                   \
    {                                                                       \
        float tgt, dd, mse = 0.f;                                           \
        tgt = ((mv) >= WALL_COT) ? 0.f : (b0); dd = (a0) - tgt; mse += dd*dd; \
        tgt = ((mv) >= WALL_COT) ? 0.f : (b1); dd = (a1) - tgt; mse += dd*dd; \
        tgt = ((mv) >= WALL_COT) ? 0.f : (b2); dd = (a2) - tgt; mse += dd*dd; \
        if ((mv) > 0.f) { num += mse; den += 1.f; }                         \
    }
    BPIX(mB0.x, o00.x, o01.x, o02.x, i00.x, i01.x, i02.x)
    BPIX(mB0.y, o00.y, o01.y, o02.y, i00.y, i01.y, i02.y)
    BPIX(mB0.z, o00.z, o01.z, o02.z, i00.z, i01.z, i02.z)
    BPIX(mB0.w, o00.w, o01.w, o02.w, i00.w, i01.w, i02.w)
    BPIX(mB1.x, o10.x, o11.x, o12.x, i10.x, i11.x, i12.x)
    BPIX(mB1.y, o10.y, o11.y, o12.y, i10.y, i11.y, i12.y)
    BPIX(mB1.z, o10.z, o11.z, o12.z, i10.z, i11.z, i12.z)
    BPIX(mB1.w, o10.w, o11.w, o12.w, i10.w, i11.w, i12.w)
#undef BPIX

    // ====== CONSUME A: 8 channels per px (stage0 + stage1 merged in regs) ======
    {
        float t0, t1, t2, t3, u0, u1, u2, u3;
#define APIX(f)                                                             \
        t0 = e00.f - d00.f; t1 = e01.f - d01.f;                             \
        t2 = e02.f - d02.f; t3 = e03.f - d03.f;                             \
        u0 = e10.f - d10.f; u1 = e11.f - d11.f;                             \
        u2 = e12.f - d12.f; u3 = e13.f - d13.f;
        APIX(x)
        const float p0 = (t0*t0 + t1*t1 + t2*t2 + t3*t3 +
                          u0*u0 + u1*u1 + u2*u2 + u3*u3) * (1.0f / (float)CFEAT);
        APIX(y)
        const float p1 = (t0*t0 + t1*t1 + t2*t2 + t3*t3 +
                          u0*u0 + u1*u1 + u2*u2 + u3*u3) * (1.0f / (float)CFEAT);
        APIX(z)
        const float p2 = (t0*t0 + t1*t1 + t2*t2 + t3*t3 +
                          u0*u0 + u1*u1 + u2*u2 + u3*u3) * (1.0f / (float)CFEAT);
        APIX(w)
        const float p3 = (t0*t0 + t1*t1 + t2*t2 + t3*t3 +
                          u0*u0 + u1*u1 + u2*u2 + u3*u3) * (1.0f / (float)CFEAT);
#undef APIX
        atomicAdd(&s_sumW[w][s0], p0);
        atomicAdd(&s_sumW[w][s1], p1);
        atomicAdd(&s_sumW[w][s2], p2);
        atomicAdd(&s_sumW[w][s3], p3);
        if (duty) {
            atomicAdd(&s_cnt[s0], 1.f); if (mk0 > 0.f && mk0 < WALL_COT) atomicAdd(&s_pos[s0], 1.f);
            atomicAdd(&s_cnt[s1], 1.f); if (mk1 > 0.f && mk1 < WALL_COT) atomicAdd(&s_pos[s1], 1.f);
            atomicAdd(&s_cnt[s2], 1.f); if (mk2 > 0.f && mk2 < WALL_COT) atomicAdd(&s_pos[s2], 1.f);
            atomicAdd(&s_cnt[s3], 1.f); if (mk3 > 0.f && mk3 < WALL_COT) atomicAdd(&s_pos[s3], 1.f);
        }
    }

    // ---- B wave reduce -> per-block partial (plain store) ----
#pragma unroll
    for (int off = 32; off >= 1; off >>= 1) {
        num += __shfl_down(num, off);
        den += __shfl_down(den, off);
    }
    if (l == 0) { s_rn[w] = num; s_rd[w] = den; }
    __syncthreads();

    if (tid == 0) {
        ws[WS_BNUM + blockIdx.x] = s_rn[0] + s_rn[1] + s_rn[2] + s_rn[3];
        ws[WS_BDEN + blockIdx.x] = s_rd[0] + s_rd[1] + s_rd[2] + s_rd[3];
    }
    if (tid < NSEG) {
        const int rep = blockIdx.x & (NREP - 1);
        float* bins = ws + rep * (3 * NBSEG);
        const int gb = ba * NSEG + tid;
        const float sv = s_sumW[0][tid] + s_sumW[1][tid] + s_sumW[2][tid] + s_sumW[3][tid];
        if (sv != 0.f) atomicAdd(&bins[NBSEG + gb], sv);
        const float cv = s_cnt[tid];
        if (cv != 0.f) atomicAdd(&bins[gb], cv);
        const float pv = s_pos[tid];
        if (pv != 0.f) atomicAdd(&bins[2 * NBSEG + gb], pv);
    }
}

__global__ __launch_bounds__(512) void confloss_finalize_kernel(
    const float* __restrict__ ws, float* __restrict__ out)
{
    const int t = threadIdx.x;   // one per (b,seg); also 2 B-partials each
    float rn = 0.f, rd = 0.f;
#pragma unroll
    for (int k = 0; k < NBLK / 512; ++k) {
        rn += ws[WS_BNUM + t + k * 512];
        rd += ws[WS_BDEN + t + k * 512];
    }
    float cnt = 0.f, sum = 0.f, pos = 0.f;
#pragma unroll
    for (int rep = 0; rep < NREP; ++rep) {
        const float* bins = ws + rep * (3 * NBSEG);
        cnt += bins[t];
        sum += bins[NBSEG + t];
        pos += bins[2 * NBSEG + t];
    }
    const float safe = fmaxf(cnt, 1.0f);
    const float mean = sum / safe;
    const bool valid = (cnt / (float)HWE) >= MIN_FRAC;
    const bool posf  = (pos / safe) > MIN_FRAC;
    float sel = (valid && posf) ? 1.0f : 0.0f;
    float val = mean * sel;

#pragma unroll
    for (int off = 32; off >= 1; off >>= 1) {
        val += __shfl_down(val, off);
        sel += __shfl_down(sel, off);
        rn  += __shfl_down(rn,  off);
        rd  += __shfl_down(rd,  off);
    }
    __shared__ float sv[8], ss[8], sn[8], sd[8];
    const int wid = t >> 6;
    if ((t & 63) == 0) { sv[wid] = val; ss[wid] = sel; sn[wid] = rn; sd[wid] = rd; }
    __syncthreads();
    if (t == 0) {
        float tv = 0.f, ts = 0.f, tn = 0.f, td = 0.f;
#pragma unroll
        for (int k = 0; k < 8; ++k) { tv += sv[k]; ts += ss[k]; tn += sn[k]; td += sd[k]; }
        const float flat_pos_mean = tv / fmaxf(ts, 1.0f);
        const float loss_recov = tn / fmaxf(td, 1.0f);
        out[0] = loss_recov + flat_pos_mean;
    }
}

extern "C" void kernel_launch(void* const* d_in, const int* in_sizes, int n_in,
                              void* d_out, int out_size, void* d_ws, size_t ws_size,
                              hipStream_t stream) {
    const float* outputs = (const float*)d_in[0];
    const float* inputs  = (const float*)d_in[1];
    const float* enc1    = (const float*)d_in[2];
    const float* dec1    = (const float*)d_in[3];
    const float* masks   = (const float*)d_in[4];
    const int*   segs    = (const int*)d_in[5];
    float* ws  = (float*)d_ws;
    float* out = (float*)d_out;

    // atomic bins must be zeroed every call
    hipMemsetAsync(ws, 0, WS_ZERO_FLOATS * sizeof(float), stream);

    confloss_main_kernel<<<NBLK, 256, 0, stream>>>(
        outputs, inputs, enc1, dec1, masks, segs, ws);
    confloss_finalize_kernel<<<1, 512, 0, stream>>>(ws, out);
}